// Round 11
// baseline (378.371 us; speedup 1.0000x reference)
//
#include <hip/hip_runtime.h>
#include <hip/hip_bf16.h>

#define HIDDEN 1024
#define B_SZ 32
#define S_SZ 2048
#define M_TOT (B_SZ * S_SZ)          // 65536 rows
#define MASKED_BIAS -10000.0f

using bf16   = __bf16;
using bf16x4 = __attribute__((ext_vector_type(4))) __bf16;
using bf16x8 = __attribute__((ext_vector_type(8))) __bf16;
using f32x4  = __attribute__((ext_vector_type(4))) float;

__device__ __forceinline__ float tanh_fast(float x) {
    float xc = fminf(fmaxf(x, -15.f), 15.f);
    float e2 = __expf(2.f * xc);
    return (e2 - 1.f) * __frcp_rn(e2 + 1.f);
}

// ---------------------------------------------------------------------------
// Kernel 0: W_K f32 -> bf16 (2 MB, L2-resident B operand)
// ---------------------------------------------------------------------------
__global__ __launch_bounds__(256) void k_wconv(
    const float* __restrict__ W, bf16* __restrict__ out)
{
    int i = blockIdx.x * 256 + threadIdx.x;
    const float4* p = (const float4*)W + (size_t)i * 2;
    float4 a = p[0], b = p[1];
    bf16x8 v = { (bf16)a.x, (bf16)a.y, (bf16)a.z, (bf16)a.w,
                 (bf16)b.x, (bf16)b.y, (bf16)b.z, (bf16)b.w };
    *(bf16x8*)(out + (size_t)i * 8) = v;
}

// ---------------------------------------------------------------------------
// Kernel 1: hl_plus[b][g] = dot(h[b,:], W_h[g,:]) + b_h[g] + b_K[g] + b_cov[g]
// ---------------------------------------------------------------------------
__global__ __launch_bounds__(256) void k_hlplus(
    const float* __restrict__ h, const float* __restrict__ W_h,
    const float* __restrict__ b_h, const float* __restrict__ b_K,
    const float* __restrict__ b_cov, float* __restrict__ hl_plus)
{
    int wid  = blockIdx.x * 4 + (threadIdx.x >> 6);
    int lane = threadIdx.x & 63;
    int b = wid & 31;
    int g = wid >> 5;
    const float4* hv = (const float4*)(h + b * HIDDEN);
    const float4* wv = (const float4*)(W_h + g * HIDDEN);
    float acc = 0.f;
#pragma unroll
    for (int i = 0; i < 4; ++i) {
        float4 a = hv[i * 64 + lane];
        float4 w = wv[i * 64 + lane];
        acc += a.x * w.x + a.y * w.y + a.z * w.z + a.w * w.w;
    }
#pragma unroll
    for (int off = 32; off; off >>= 1) acc += __shfl_xor(acc, off);
    if (lane == 0)
        hl_plus[b * HIDDEN + g] = acc + b_h[g] + b_K[g] + b_cov[g];
}

// ===========================================================================
// Kernel 2 (R11): R10 skeleton, but A staged DIRECTLY FROM f32 K via
// global_load_lds into an f32 LDS tile (no k_kconv prepass, no Kbf).
// Fragments read as 2x b128 f32 and converted to bf16 in-register (scalar
// casts -> compiler cvt_pk). B stays bf16 (2 MB wconv prepass).
// 128x128 tile, BK=32, 256 threads = 4 waves (2M x 2N, wave tile 64x64),
// LDS ~50 KB -> 3 blocks/CU. One __syncthreads per K-tile.
// A swizzle (128B rows, 8 chunks): LDS slot s of row r = global chunk
// s ^ (r&7); read chunk c at slot c ^ (lr&7)  -> 2 lanes/bank (free).
// B swizzle (64B rows):  slot s of row r = global chunk s ^ ((r>>1)&3)
// (R7/R10-proven, conflicts == 0).
// ===========================================================================
#define NT_N 8

__global__ __launch_bounds__(256, 4) void k_fusedF(
    const float* __restrict__ Kin,      // [65536][1024] f32
    const bf16*  __restrict__ Bbf,      // [1024][1024] bf16 (W_K)
    const float* __restrict__ hl_plus,
    const float* __restrict__ W_cov,
    const float* __restrict__ cov,
    const float* __restrict__ W_v,
    float* __restrict__ e_part)         // [8][65536]
{
    __shared__ __align__(16) float As[2][128][32];  // 32 KB (f32)
    __shared__ __align__(16) bf16  Bs[2][128][32];  // 16 KB
    __shared__ float e_buf[128][2];                 // 1 KB

    const int tid = threadIdx.x;
    const int bid = blockIdx.x;
    // XCD-bijective swizzle: 4096 blocks, 512/XCD, nt fastest within XCD.
    const int lid = (bid & 7) * 512 + (bid >> 3);
    const int mt  = lid >> 3;            // 512 m-tiles (128 rows)
    const int nt  = lid & 7;             // 8 n-tiles (128 cols)
    const int row0 = mt * 128;
    const int col0 = nt * 128;

    const int w    = tid >> 6;           // wave 0..3
    const int lane = tid & 63;
    const int wm   = w >> 1;             // M-half (64 rows)
    const int wn   = w & 1;              // N-half (64 cols)
    const int lr   = lane & 15;
    const int kb   = lane >> 4;
    // B read col (bf16 elems): chunk kb at slot kb ^ ((lr>>1)&3)
    const int colB = (kb ^ ((lr >> 1) & 3)) * 8;
    // A read cols (f32 elems): chunks 2kb, 2kb+1 at slot ^ (lr&7)
    const int cA0  = ((2 * kb)     ^ (lr & 7)) * 4;
    const int cA1  = ((2 * kb + 1) ^ (lr & 7)) * 4;

    // ---- A staging: 4 instrs/wave; instr covers 8 rows x 8 chunks(16B).
    //      lane l -> row l>>3, slot l&7, src chunk (l&7)^((l>>3)&7)
    const int arow = lane >> 3;                       // 0..7
    const int agch = (lane & 7) ^ arow;               // pre-swizzled chunk
    const float* Abase =
        Kin + (size_t)(row0 + w * 32 + arow) * HIDDEN + agch * 4;
    // ---- B staging: 2 instrs/wave; instr covers 16 rows x 4 chunks.
    //      lane l -> row l>>2, slot l&3, src chunk (l&3)^((l>>3)&3)
    const int brow = lane >> 2;                       // 0..15
    const int bgch = (lane & 3) ^ ((lane >> 3) & 3);
    const bf16* Bbase =
        Bbf + (size_t)(col0 + w * 16 + brow) * HIDDEN + bgch * 8;

    f32x4 acc[4][4] = {};

#define GL(SRC, DST) __builtin_amdgcn_global_load_lds(                    \
        (const __attribute__((address_space(1))) void*)(SRC),             \
        (__attribute__((address_space(3))) void*)(DST), 16, 0, 0);

#define STAGE(KT, BUF)                                                    \
    GL(Abase + (KT) * 32,                        &As[BUF][w * 32][0])     \
    GL(Abase + (size_t)8  * HIDDEN + (KT) * 32,  &As[BUF][w * 32 +  8][0])\
    GL(Abase + (size_t)16 * HIDDEN + (KT) * 32,  &As[BUF][w * 32 + 16][0])\
    GL(Abase + (size_t)24 * HIDDEN + (KT) * 32,  &As[BUF][w * 32 + 24][0])\
    GL(Bbase + (KT) * 32,                        &Bs[BUF][w * 16][0])     \
    GL(Bbase + (size_t)64 * HIDDEN + (KT) * 32,  &Bs[BUF][64 + w * 16][0])

#define TILE_COMPUTE(BUF)                                                 \
    {                                                                     \
        bf16x8 afr[4], bfr[4];                                            \
        _Pragma("unroll") for (int j = 0; j < 4; ++j) {                   \
            const float* rp = &As[BUF][wm * 64 + j * 16 + lr][0];         \
            f32x4 a0 = *(const f32x4*)(rp + cA0);                         \
            f32x4 a1 = *(const f32x4*)(rp + cA1);                         \
            bf16x8 t = { (bf16)a0[0], (bf16)a0[1], (bf16)a0[2],           \
                         (bf16)a0[3], (bf16)a1[0], (bf16)a1[1],           \
                         (bf16)a1[2], (bf16)a1[3] };                      \
            afr[j] = t;                                                   \
        }                                                                 \
        _Pragma("unroll") for (int n = 0; n < 4; ++n)                     \
            bfr[n] = *(const bf16x8*)&Bs[BUF][wn * 64 + n * 16 + lr][colB];\
        __builtin_amdgcn_s_setprio(1);                                    \
        _Pragma("unroll") for (int j = 0; j < 4; ++j)                     \
            _Pragma("unroll") for (int n = 0; n < 4; ++n)                 \
                acc[j][n] = __builtin_amdgcn_mfma_f32_16x16x32_bf16(      \
                    afr[j], bfr[n], acc[j][n], 0, 0, 0);                  \
        __builtin_amdgcn_s_setprio(0);                                    \
    }

    // prologue: stage tile 0 into buf0 (drained by __syncthreads)
    STAGE(0, 0)
    __syncthreads();

    // tiles 0..29 (stage t+1 each; one barrier per tile)
    for (int i = 0; i < 15; ++i) {
        const int t = i * 2;
        STAGE(t + 1, 1)          // tile t   reads buf0, stages t+1 -> buf1
        TILE_COMPUTE(0)
        __syncthreads();
        STAGE(t + 2, 0)          // tile t+1 reads buf1, stages t+2 -> buf0
        TILE_COMPUTE(1)
        __syncthreads();
    }
    // tile 30: stage 31 -> buf1
    STAGE(31, 1)
    TILE_COMPUTE(0)
    __syncthreads();
    // tile 31: compute only
    TILE_COMPUTE(1)

    // ------------------- epilogue: tanh + dot(W_v) reduction ----------------
    const int bidx = row0 >> 11;          // 128-row tiles never straddle batch
    float hlv[4], wcv[4], wvv[4];
#pragma unroll
    for (int n = 0; n < 4; ++n) {
        int g = col0 + wn * 64 + n * 16 + lr;
        hlv[n] = hl_plus[bidx * HIDDEN + g];
        wcv[n] = W_cov[g];
        wvv[n] = W_v[g];
    }
#pragma unroll
    for (int j = 0; j < 4; ++j) {
#pragma unroll
        for (int i = 0; i < 4; ++i) {
            int rloc = wm * 64 + j * 16 + kb * 4 + i;
            float cv = cov[row0 + rloc];
            float ep = 0.f;
#pragma unroll
            for (int n = 0; n < 4; ++n) {
                float arg = acc[j][n][i] + hlv[n] + cv * wcv[n];
                ep += tanh_fast(arg) * wvv[n];
            }
            ep += __shfl_xor(ep, 1);
            ep += __shfl_xor(ep, 2);
            ep += __shfl_xor(ep, 4);
            ep += __shfl_xor(ep, 8);
            if (lr == 0) e_buf[rloc][wn] = ep;
        }
    }
    __syncthreads();
    if (tid < 128)
        e_part[(size_t)nt * M_TOT + row0 + tid] = e_buf[tid][0] + e_buf[tid][1];

#undef GL
#undef STAGE
#undef TILE_COMPUTE
}

// ---------------------------------------------------------------------------
// Kernel 3: per-batch softmax over S=2048; also emits cov_new = cov + a
// ---------------------------------------------------------------------------
__global__ __launch_bounds__(256) void k_softmax(
    const float* __restrict__ e_part, const float* __restrict__ mask,
    const float* __restrict__ cov, const float* __restrict__ b_v,
    float* __restrict__ a_out, float* __restrict__ cov_out)
{
    __shared__ float red[8];
    int b = blockIdx.x, tid = threadIdx.x;
    float bv = b_v[0];
    float ev[8];
    float mx = -1e30f;
#pragma unroll
    for (int j = 0; j < 8; ++j) {
        int s = j * 256 + tid;
        int idx = b * S_SZ + s;
        float e = bv;
#pragma unroll
        for (int p = 0; p < 8; ++p) e += e_part[(size_t)p * M_TOT + idx];
        e += mask[idx] * MASKED_BIAS;
        ev[j] = e;
        mx = fmaxf(mx, e);
    }
#pragma unroll
    for (int off = 32; off; off >>= 1) mx = fmaxf(mx, __shfl_xor(mx, off));
    if ((tid & 63) == 0) red[tid >> 6] = mx;
    __syncthreads();
    mx = fmaxf(fmaxf(red[0], red[1]), fmaxf(red[2], red[3]));
    float sum = 0.f;
#pragma unroll
    for (int j = 0; j < 8; ++j) { ev[j] = __expf(ev[j] - mx); sum += ev[j]; }
#pragma unroll
    for (int off = 32; off; off >>= 1) sum += __shfl_xor(sum, off);
    if ((tid & 63) == 0) red[4 + (tid >> 6)] = sum;
    __syncthreads();
    sum = red[4] + red[5] + red[6] + red[7];
    float inv = 1.f / sum;
#pragma unroll
    for (int j = 0; j < 8; ++j) {
        int idx = b * S_SZ + j * 256 + tid;
        float a = ev[j] * inv;
        a_out[idx]   = a;
        cov_out[idx] = cov[idx] + a;
    }
}

// ---------------------------------------------------------------------------
// Kernel 4: context partials  part_out[b][sc][h] = sum_{s in chunk} a*K
// (f32 K; L2/L3-warm after the GEMM streamed it)
// ---------------------------------------------------------------------------
__global__ __launch_bounds__(256) void k_ctx_part(
    const float* __restrict__ Kin, const float* __restrict__ a_out,
    float* __restrict__ part_out)
{
    int sc = blockIdx.x;   // 0..7
    int b  = blockIdx.y;   // 0..31
    int tid = threadIdx.x;
    const float4* Kb = (const float4*)(Kin + ((size_t)b * S_SZ + sc * 256) * HIDDEN);
    const float*  ab = a_out + b * S_SZ + sc * 256;
    float4 acc = {0.f, 0.f, 0.f, 0.f};
#pragma unroll 4
    for (int s = 0; s < 256; ++s) {
        float av = ab[s];
        float4 kv = Kb[(size_t)s * 256 + tid];
        acc.x += av * kv.x; acc.y += av * kv.y;
        acc.z += av * kv.z; acc.w += av * kv.w;
    }
    ((float4*)part_out)[((size_t)b * 8 + sc) * 256 + tid] = acc;
}

// ---------------------------------------------------------------------------
// Kernel 5: out[b][h] = sum_sc part_out[b][sc][h]
// ---------------------------------------------------------------------------
__global__ __launch_bounds__(256) void k_ctx_reduce(
    const float* __restrict__ part_out, float* __restrict__ out, int nc)
{
    int b = blockIdx.x, tid = threadIdx.x;
    float4 acc = {0.f, 0.f, 0.f, 0.f};
    for (int sc = 0; sc < nc; ++sc) {
        float4 v = ((const float4*)part_out)[((size_t)b * nc + sc) * 256 + tid];
        acc.x += v.x; acc.y += v.y; acc.z += v.z; acc.w += v.w;
    }
    ((float4*)out)[b * 256 + tid] = acc;
}

// ---------------------------------------------------------------------------
extern "C" void kernel_launch(void* const* d_in, const int* in_sizes, int n_in,
                              void* d_out, int out_size, void* d_ws, size_t ws_size,
                              hipStream_t stream)
{
    const float* h     = (const float*)d_in[0];
    const float* Kin   = (const float*)d_in[1];
    const float* cov   = (const float*)d_in[2];
    const float* mask  = (const float*)d_in[3];
    const float* W_h   = (const float*)d_in[4];
    const float* b_h   = (const float*)d_in[5];
    const float* W_K   = (const float*)d_in[6];
    const float* b_K   = (const float*)d_in[7];
    const float* W_cov = (const float*)d_in[8];
    const float* b_cov = (const float*)d_in[9];
    const float* W_v   = (const float*)d_in[10];
    const float* b_v   = (const float*)d_in[11];

    float* out_ctx = (float*)d_out;            // 32*1024
    float* a_out   = out_ctx + B_SZ * HIDDEN;  // 32*2048
    float* cov_out = a_out + M_TOT;            // 32*2048

    float* ws       = (float*)d_ws;
    float* hl_plus  = ws;                        // 32768 f32
    float* e_part   = ws + 32768;                // 8*65536 f32 = 2 MB
    float* part_out = e_part;                    // alias (sequential use, 1 MB)
    bf16*  Bbf      = (bf16*)(e_part + 8 * M_TOT);   // 2 MB
    // total ws use: ~4.2 MB (no Kbf anymore)

    k_wconv<<<512, 256, 0, stream>>>(W_K, Bbf);
    k_hlplus<<<8192, 256, 0, stream>>>(h, W_h, b_h, b_K, b_cov, hl_plus);
    k_fusedF<<<512 * NT_N, 256, 0, stream>>>(
        Kin, Bbf, hl_plus, W_cov, cov, W_v, e_part);
    k_softmax<<<B_SZ, 256, 0, stream>>>(e_part, mask, cov, b_v, a_out, cov_out);
    dim3 g4(8, B_SZ);
    k_ctx_part<<<g4, 256, 0, stream>>>(Kin, a_out, part_out);
    k_ctx_reduce<<<B_SZ, 256, 0, stream>>>(part_out, out_ctx, 8);
}

// Round 12
// 312.674 us; speedup vs baseline: 1.2101x; 1.2101x over previous
//
#include <hip/hip_runtime.h>
#include <hip/hip_bf16.h>

#define HIDDEN 1024
#define B_SZ 32
#define S_SZ 2048
#define M_TOT (B_SZ * S_SZ)          // 65536 rows
#define MASKED_BIAS -10000.0f

using bf16   = __bf16;
using bf16x4 = __attribute__((ext_vector_type(4))) __bf16;
using bf16x8 = __attribute__((ext_vector_type(8))) __bf16;
using f32x4  = __attribute__((ext_vector_type(4))) float;

__device__ __forceinline__ float tanh_fast(float x) {
    float xc = fminf(fmaxf(x, -15.f), 15.f);
    float e2 = __expf(2.f * xc);
    return (e2 - 1.f) * __frcp_rn(e2 + 1.f);
}

// ---------------------------------------------------------------------------
// Kernel 0a: W_K f32 -> bf16 (2 MB, L2-resident B operand)
// ---------------------------------------------------------------------------
__global__ __launch_bounds__(256) void k_wconv(
    const float* __restrict__ W, bf16* __restrict__ out)
{
    int i = blockIdx.x * 256 + threadIdx.x;
    const float4* p = (const float4*)W + (size_t)i * 2;
    float4 a = p[0], b = p[1];
    bf16x8 v = { (bf16)a.x, (bf16)a.y, (bf16)a.z, (bf16)a.w,
                 (bf16)b.x, (bf16)b.y, (bf16)b.z, (bf16)b.w };
    *(bf16x8*)(out + (size_t)i * 8) = v;
}

// ---------------------------------------------------------------------------
// Kernel 0b: K f32 -> bf16 (128 MB A operand)
// ---------------------------------------------------------------------------
__global__ __launch_bounds__(256) void k_kconv(
    const float* __restrict__ K, bf16* __restrict__ out)
{
    size_t i = (size_t)blockIdx.x * 256 + threadIdx.x;
    const float4* p = (const float4*)K + i * 2;
    float4 a = p[0], b = p[1];
    bf16x8 v = { (bf16)a.x, (bf16)a.y, (bf16)a.z, (bf16)a.w,
                 (bf16)b.x, (bf16)b.y, (bf16)b.z, (bf16)b.w };
    *(bf16x8*)(out + i * 8) = v;
}

// ---------------------------------------------------------------------------
// Kernel 1: hl_plus[b][g] = dot(h[b,:], W_h[g,:]) + b_h[g] + b_K[g] + b_cov[g]
// ---------------------------------------------------------------------------
__global__ __launch_bounds__(256) void k_hlplus(
    const float* __restrict__ h, const float* __restrict__ W_h,
    const float* __restrict__ b_h, const float* __restrict__ b_K,
    const float* __restrict__ b_cov, float* __restrict__ hl_plus)
{
    int wid  = blockIdx.x * 4 + (threadIdx.x >> 6);
    int lane = threadIdx.x & 63;
    int b = wid & 31;
    int g = wid >> 5;
    const float4* hv = (const float4*)(h + b * HIDDEN);
    const float4* wv = (const float4*)(W_h + g * HIDDEN);
    float acc = 0.f;
#pragma unroll
    for (int i = 0; i < 4; ++i) {
        float4 a = hv[i * 64 + lane];
        float4 w = wv[i * 64 + lane];
        acc += a.x * w.x + a.y * w.y + a.z * w.z + a.w * w.w;
    }
#pragma unroll
    for (int off = 32; off; off >>= 1) acc += __shfl_xor(acc, off);
    if (lane == 0)
        hl_plus[b * HIDDEN + g] = acc + b_h[g] + b_K[g] + b_cov[g];
}

// ===========================================================================
// Kernel 2 (R12): R10 skeleton + 3-deep LDS pipeline with COUNTED vmcnt (T4).
// 128x128 tile, BK=32, 256 threads = 4 waves (2M x 2N, wave tile 64x64).
// Tile t: issue STAGE(t+2)->buf[(t+2)%3]; ds_read buf[t%3]; MFMA;
//         s_waitcnt vmcnt(4)  (waits stage(t+1), issued one full tile ago;
//         stage(t+2) stays in flight ACROSS the barrier); raw s_barrier.
// Never vmcnt(0) in steady state. LDS 49 KB -> 3 blocks/CU.
// Hazards: RAW buf[t%3] via VM(4)+barrier at t-1; WAR: stage(t+2) issued
// after end-of-(t-1) barrier where all readers of that buffer retired.
// Staging via global_load_lds from bf16; R7/R10-proven conflict-free swizzle:
// LDS[row][chunk c] = global chunk c ^ ((row>>1)&3).
// ===========================================================================
#define NT_N 8

__global__ __launch_bounds__(256, 3) void k_fusedB(
    const bf16*  __restrict__ Kbf,      // [65536][1024] bf16
    const bf16*  __restrict__ Bbf,      // [1024][1024] bf16 (W_K)
    const float* __restrict__ hl_plus,
    const float* __restrict__ W_cov,
    const float* __restrict__ cov,
    const float* __restrict__ W_v,
    float* __restrict__ e_part)         // [8][65536]
{
    __shared__ __align__(16) bf16 As[3][128][32];   // 24 KB
    __shared__ __align__(16) bf16 Bs[3][128][32];   // 24 KB
    __shared__ float e_buf[128][2];                 // 1 KB

    const int tid = threadIdx.x;
    const int bid = blockIdx.x;
    // XCD-bijective swizzle: 4096 blocks, 512/XCD, nt fastest within XCD.
    const int lid = (bid & 7) * 512 + (bid >> 3);
    const int mt  = lid >> 3;            // 512 m-tiles (128 rows)
    const int nt  = lid & 7;             // 8 n-tiles (128 cols)
    const int row0 = mt * 128;
    const int col0 = nt * 128;

    const int w    = tid >> 6;           // wave 0..3
    const int lane = tid & 63;
    const int wm   = w >> 1;             // M-half (64 rows)
    const int wn   = w & 1;              // N-half (64 cols)
    const int lr   = lane & 15;
    const int kb   = lane >> 4;
    const int colA = (kb ^ ((lr >> 1) & 3)) * 8;   // read-side swizzled col

    // stage geometry: one gload instr per wave = 16 rows x 64B (4x16B chunks);
    // source chunk pre-swizzled: lane l -> chunk (l&3) ^ ((l>>3)&3).
    // 4 waves cover 64 rows per issue; 2 issues each for A(128) and B(128).
    const int srow = lane >> 2;
    const int gch  = (lane & 3) ^ ((lane >> 3) & 3);
    const bf16* Abase = Kbf + (size_t)(row0 + w * 16 + srow) * HIDDEN + gch * 8;
    const bf16* Bbase = Bbf + (size_t)(col0 + w * 16 + srow) * HIDDEN + gch * 8;

    f32x4 acc[4][4] = {};

    // 4 gload instrs per thread per STAGE -> vmcnt granularity 4
#define STAGE(KT, BUF)                                                    \
    __builtin_amdgcn_global_load_lds(                                     \
        (const __attribute__((address_space(1))) void*)(Abase + (KT) * 32),\
        (__attribute__((address_space(3))) void*)&As[BUF][w * 16][0],     \
        16, 0, 0);                                                        \
    __builtin_amdgcn_global_load_lds(                                     \
        (const __attribute__((address_space(1))) void*)                   \
            (Abase + (size_t)64 * HIDDEN + (KT) * 32),                    \
        (__attribute__((address_space(3))) void*)&As[BUF][64 + w * 16][0],\
        16, 0, 0);                                                        \
    __builtin_amdgcn_global_load_lds(                                     \
        (const __attribute__((address_space(1))) void*)(Bbase + (KT) * 32),\
        (__attribute__((address_space(3))) void*)&Bs[BUF][w * 16][0],     \
        16, 0, 0);                                                        \
    __builtin_amdgcn_global_load_lds(                                     \
        (const __attribute__((address_space(1))) void*)                   \
            (Bbase + (size_t)64 * HIDDEN + (KT) * 32),                    \
        (__attribute__((address_space(3))) void*)&Bs[BUF][64 + w * 16][0],\
        16, 0, 0);

#define TILE_COMPUTE(BUF)                                                 \
    {                                                                     \
        bf16x8 afr[4], bfr[4];                                            \
        _Pragma("unroll") for (int j = 0; j < 4; ++j)                     \
            afr[j] = *(const bf16x8*)                                     \
                &As[BUF][wm * 64 + j * 16 + lr][colA];                    \
        _Pragma("unroll") for (int n = 0; n < 4; ++n)                     \
            bfr[n] = *(const bf16x8*)&Bs[BUF][wn * 64 + n * 16 + lr][colA];\
        __builtin_amdgcn_s_setprio(1);                                    \
        _Pragma("unroll") for (int j = 0; j < 4; ++j)                     \
            _Pragma("unroll") for (int n = 0; n < 4; ++n)                 \
                acc[j][n] = __builtin_amdgcn_mfma_f32_16x16x32_bf16(      \
                    afr[j], bfr[n], acc[j][n], 0, 0, 0);                  \
        __builtin_amdgcn_s_setprio(0);                                    \
    }

#define VM(n)   asm volatile("s_waitcnt vmcnt(" #n ")" ::: "memory")
#define PBAR()  do { asm volatile("" ::: "memory");                       \
                     __builtin_amdgcn_s_barrier();                        \
                     asm volatile("" ::: "memory"); } while (0)

    // ---- prologue: stage tiles 0,1; wait tile 0 only (tile 1 in flight) ----
    STAGE(0, 0)
    STAGE(1, 1)
    VM(4); PBAR();

    // ---- tiles 0..29, buffers cycle 0,1,2 (unrolled x3: indices static) ----
    for (int i = 0; i < 10; ++i) {
        const int t = i * 3;
        STAGE(t + 2, 2) TILE_COMPUTE(0) VM(4); PBAR();
        STAGE(t + 3, 0) TILE_COMPUTE(1) VM(4); PBAR();
        STAGE(t + 4, 1) TILE_COMPUTE(2) VM(4); PBAR();
    }
    // loop stages tiles 2..31 (i=9: stages 29,30,31), computes 0..29.
    // ---- tile 30 (buf0): nothing to stage; drain stage(31) ----
    TILE_COMPUTE(0) VM(0); PBAR();
    // ---- tile 31 (buf1): compute only ----
    TILE_COMPUTE(1)

    // ------------------- epilogue: tanh + dot(W_v) reduction ----------------
    const int bidx = row0 >> 11;          // 128-row tiles never straddle batch
    float hlv[4], wcv[4], wvv[4];
#pragma unroll
    for (int n = 0; n < 4; ++n) {
        int g = col0 + wn * 64 + n * 16 + lr;
        hlv[n] = hl_plus[bidx * HIDDEN + g];
        wcv[n] = W_cov[g];
        wvv[n] = W_v[g];
    }
#pragma unroll
    for (int j = 0; j < 4; ++j) {
#pragma unroll
        for (int i = 0; i < 4; ++i) {
            int rloc = wm * 64 + j * 16 + kb * 4 + i;
            float cv = cov[row0 + rloc];
            float ep = 0.f;
#pragma unroll
            for (int n = 0; n < 4; ++n) {
                float arg = acc[j][n][i] + hlv[n] + cv * wcv[n];
                ep += tanh_fast(arg) * wvv[n];
            }
            ep += __shfl_xor(ep, 1);
            ep += __shfl_xor(ep, 2);
            ep += __shfl_xor(ep, 4);
            ep += __shfl_xor(ep, 8);
            if (lr == 0) e_buf[rloc][wn] = ep;
        }
    }
    __syncthreads();
    if (tid < 128)
        e_part[(size_t)nt * M_TOT + row0 + tid] = e_buf[tid][0] + e_buf[tid][1];

#undef STAGE
#undef TILE_COMPUTE
#undef VM
#undef PBAR
}

// ---------------------------------------------------------------------------
// Kernel 3: per-batch softmax over S=2048; also emits cov_new = cov + a
// ---------------------------------------------------------------------------
__global__ __launch_bounds__(256) void k_softmax(
    const float* __restrict__ e_part, const float* __restrict__ mask,
    const float* __restrict__ cov, const float* __restrict__ b_v,
    float* __restrict__ a_out, float* __restrict__ cov_out)
{
    __shared__ float red[8];
    int b = blockIdx.x, tid = threadIdx.x;
    float bv = b_v[0];
    float ev[8];
    float mx = -1e30f;
#pragma unroll
    for (int j = 0; j < 8; ++j) {
        int s = j * 256 + tid;
        int idx = b * S_SZ + s;
        float e = bv;
#pragma unroll
        for (int p = 0; p < 8; ++p) e += e_part[(size_t)p * M_TOT + idx];
        e += mask[idx] * MASKED_BIAS;
        ev[j] = e;
        mx = fmaxf(mx, e);
    }
#pragma unroll
    for (int off = 32; off; off >>= 1) mx = fmaxf(mx, __shfl_xor(mx, off));
    if ((tid & 63) == 0) red[tid >> 6] = mx;
    __syncthreads();
    mx = fmaxf(fmaxf(red[0], red[1]), fmaxf(red[2], red[3]));
    float sum = 0.f;
#pragma unroll
    for (int j = 0; j < 8; ++j) { ev[j] = __expf(ev[j] - mx); sum += ev[j]; }
#pragma unroll
    for (int off = 32; off; off >>= 1) sum += __shfl_xor(sum, off);
    if ((tid & 63) == 0) red[4 + (tid >> 6)] = sum;
    __syncthreads();
    sum = red[4] + red[5] + red[6] + red[7];
    float inv = 1.f / sum;
#pragma unroll
    for (int j = 0; j < 8; ++j) {
        int idx = b * S_SZ + j * 256 + tid;
        float a = ev[j] * inv;
        a_out[idx]   = a;
        cov_out[idx] = cov[idx] + a;
    }
}

// ---------------------------------------------------------------------------
// Kernel 4: context partials from bf16 K (L3-warm after GEMM), 16 s-chunks
// ---------------------------------------------------------------------------
__global__ __launch_bounds__(256) void k_ctx_part_bf(
    const bf16* __restrict__ Kbf, const float* __restrict__ a_out,
    float* __restrict__ part_out)
{
    int sc = blockIdx.x;   // 0..15
    int b  = blockIdx.y;   // 0..31
    int tid = threadIdx.x;
    const bf16* Kb = Kbf + ((size_t)b * S_SZ + sc * 128) * HIDDEN;
    const float* ab = a_out + b * S_SZ + sc * 128;
    float4 acc = {0.f, 0.f, 0.f, 0.f};
#pragma unroll 4
    for (int s = 0; s < 128; ++s) {
        float av = ab[s];
        bf16x4 kv = *(const bf16x4*)(Kb + (size_t)s * HIDDEN + tid * 4);
        acc.x += av * (float)kv[0];
        acc.y += av * (float)kv[1];
        acc.z += av * (float)kv[2];
        acc.w += av * (float)kv[3];
    }
    ((float4*)part_out)[((size_t)b * 16 + sc) * 256 + tid] = acc;
}

// ---------------------------------------------------------------------------
// Kernel 5: out[b][h] = sum_sc part_out[b][sc][h]
// ---------------------------------------------------------------------------
__global__ __launch_bounds__(256) void k_ctx_reduce(
    const float* __restrict__ part_out, float* __restrict__ out, int nc)
{
    int b = blockIdx.x, tid = threadIdx.x;
    float4 acc = {0.f, 0.f, 0.f, 0.f};
    for (int sc = 0; sc < nc; ++sc) {
        float4 v = ((const float4*)part_out)[((size_t)b * nc + sc) * 256 + tid];
        acc.x += v.x; acc.y += v.y; acc.z += v.z; acc.w += v.w;
    }
    ((float4*)out)[b * 256 + tid] = acc;
}

// ---------------------------------------------------------------------------
extern "C" void kernel_launch(void* const* d_in, const int* in_sizes, int n_in,
                              void* d_out, int out_size, void* d_ws, size_t ws_size,
                              hipStream_t stream)
{
    const float* h     = (const float*)d_in[0];
    const float* Kin   = (const float*)d_in[1];
    const float* cov   = (const float*)d_in[2];
    const float* mask  = (const float*)d_in[3];
    const float* W_h   = (const float*)d_in[4];
    const float* b_h   = (const float*)d_in[5];
    const float* W_K   = (const float*)d_in[6];
    const float* b_K   = (const float*)d_in[7];
    const float* W_cov = (const float*)d_in[8];
    const float* b_cov = (const float*)d_in[9];
    const float* W_v   = (const float*)d_in[10];
    const float* b_v   = (const float*)d_in[11];

    float* out_ctx = (float*)d_out;            // 32*1024
    float* a_out   = out_ctx + B_SZ * HIDDEN;  // 32*2048
    float* cov_out = a_out + M_TOT;            // 32*2048

    float* ws       = (float*)d_ws;
    float* hl_plus  = ws;                        // 32768 f32
    float* e_part   = ws + 32768;                // 8*65536 f32 = 2 MB
    float* part_out = e_part;                    // alias (sequential use, 2 MB)
    bf16*  Bbf      = (bf16*)(e_part + 8 * M_TOT);          // 2 MB
    bf16*  Kbf      = (bf16*)((char*)Bbf + (size_t)HIDDEN * HIDDEN * sizeof(bf16));

    k_wconv<<<512, 256, 0, stream>>>(W_K, Bbf);
    k_hlplus<<<8192, 256, 0, stream>>>(h, W_h, b_h, b_K, b_cov, hl_plus);
    k_kconv<<<(M_TOT * HIDDEN / 8) / 256, 256, 0, stream>>>(Kin, Kbf);
    k_fusedB<<<512 * NT_N, 256, 0, stream>>>(
        Kbf, Bbf, hl_plus, W_cov, cov, W_v, e_part);
    k_softmax<<<B_SZ, 256, 0, stream>>>(e_part, mask, cov, b_v, a_out, cov_out);
    dim3 g4(16, B_SZ);
    k_ctx_part_bf<<<g4, 256, 0, stream>>>(Kbf, a_out, part_out);
    k_ctx_reduce<<<B_SZ, 256, 0, stream>>>(part_out, out_ctx, 16);
}

// Round 13
// 293.067 us; speedup vs baseline: 1.2911x; 1.0669x over previous
//
#include <hip/hip_runtime.h>
#include <hip/hip_bf16.h>

#define HIDDEN 1024
#define B_SZ 32
#define S_SZ 2048
#define M_TOT (B_SZ * S_SZ)          // 65536 rows
#define MASKED_BIAS -10000.0f

using bf16   = __bf16;
using bf16x4 = __attribute__((ext_vector_type(4))) __bf16;
using bf16x8 = __attribute__((ext_vector_type(8))) __bf16;
using f32x4  = __attribute__((ext_vector_type(4))) float;

__device__ __forceinline__ float tanh_fast(float x) {
    float xc = fminf(fmaxf(x, -15.f), 15.f);
    float e2 = __expf(2.f * xc);
    return (e2 - 1.f) * __frcp_rn(e2 + 1.f);
}

// ---------------------------------------------------------------------------
// Kernel 0: W_K f32 -> bf16 (2 MB, L2-resident B operand)
// ---------------------------------------------------------------------------
__global__ __launch_bounds__(256) void k_wconv(
    const float* __restrict__ W, bf16* __restrict__ out)
{
    int i = blockIdx.x * 256 + threadIdx.x;
    const float4* p = (const float4*)W + (size_t)i * 2;
    float4 a = p[0], b = p[1];
    bf16x8 v = { (bf16)a.x, (bf16)a.y, (bf16)a.z, (bf16)a.w,
                 (bf16)b.x, (bf16)b.y, (bf16)b.z, (bf16)b.w };
    *(bf16x8*)(out + (size_t)i * 8) = v;
}

// ---------------------------------------------------------------------------
// Kernel 1: hl_plus[b][g] = dot(h[b,:], W_h[g,:]) + b_h[g] + b_K[g] + b_cov[g]
// ---------------------------------------------------------------------------
__global__ __launch_bounds__(256) void k_hlplus(
    const float* __restrict__ h, const float* __restrict__ W_h,
    const float* __restrict__ b_h, const float* __restrict__ b_K,
    const float* __restrict__ b_cov, float* __restrict__ hl_plus)
{
    int wid  = blockIdx.x * 4 + (threadIdx.x >> 6);
    int lane = threadIdx.x & 63;
    int b = wid & 31;
    int g = wid >> 5;
    const float4* hv = (const float4*)(h + b * HIDDEN);
    const float4* wv = (const float4*)(W_h + g * HIDDEN);
    float acc = 0.f;
#pragma unroll
    for (int i = 0; i < 4; ++i) {
        float4 a = hv[i * 64 + lane];
        float4 w = wv[i * 64 + lane];
        acc += a.x * w.x + a.y * w.y + a.z * w.z + a.w * w.w;
    }
#pragma unroll
    for (int off = 32; off; off >>= 1) acc += __shfl_xor(acc, off);
    if (lane == 0)
        hl_plus[b * HIDDEN + g] = acc + b_h[g] + b_K[g] + b_cov[g];
}

// ===========================================================================
// Kernel 2 (R13): R10 skeleton (128x128, BK=32, 4 waves 2Mx2N, 4 blocks/CU,
// one __syncthreads per K-tile), but A is reg-staged DIRECTLY from f32 K
// (no kconv prepass): per thread per tile 4x global_load_dwordx4 f32 +
// cvt + 2x swizzled ds_write_b128 into the bf16 LDS tile. B stays
// global_load_lds from bf16 W (2 MB, L2-resident).
// LDS layout/swizzle identical to R10 (conflicts==0 proven):
//   LDS[row][chunk c] = global chunk c ^ ((row>>1)&3), 64B rows.
// Order per tile: issue A-f32 loads(t+1) early -> B gload(t+1) ->
// compute(t) -> cvt+ds_write A(t+1) -> __syncthreads.
// ===========================================================================
#define NT_N 8

__global__ __launch_bounds__(256, 4) void k_fusedC(
    const float* __restrict__ Kin,      // [65536][1024] f32
    const bf16*  __restrict__ Bbf,      // [1024][1024] bf16 (W_K)
    const float* __restrict__ hl_plus,
    const float* __restrict__ W_cov,
    const float* __restrict__ cov,
    const float* __restrict__ W_v,
    float* __restrict__ e_part)         // [8][65536]
{
    __shared__ __align__(16) bf16 As[2][128][32];   // 16 KB
    __shared__ __align__(16) bf16 Bs[2][128][32];   // 16 KB
    __shared__ float e_buf[128][2];                 // 1 KB

    const int tid = threadIdx.x;
    const int bid = blockIdx.x;
    // XCD-bijective swizzle: 4096 blocks, 512/XCD, nt fastest within XCD.
    const int lid = (bid & 7) * 512 + (bid >> 3);
    const int mt  = lid >> 3;            // 512 m-tiles (128 rows)
    const int nt  = lid & 7;             // 8 n-tiles (128 cols)
    const int row0 = mt * 128;
    const int col0 = nt * 128;

    const int w    = tid >> 6;           // wave 0..3
    const int lane = tid & 63;
    const int wm   = w >> 1;             // M-half (64 rows)
    const int wn   = w & 1;              // N-half (64 cols)
    const int lr   = lane & 15;
    const int kb   = lane >> 4;
    const int colA = (kb ^ ((lr >> 1) & 3)) * 8;   // read-side swizzled col

    // ---- A reg-staging geometry: thread -> row tid>>1, half h = tid&1
    //      (bf16 chunks 2h, 2h+1 of that row; f32 source cols 16h..16h+15)
    const int arow = tid >> 1;
    const int ah   = tid & 1;
    const float* Asrc = Kin + (size_t)(row0 + arow) * HIDDEN + ah * 16;
    const int aswz = (arow >> 1) & 3;
    // write slots (bf16 elem offsets) for chunks 2h, 2h+1:
    const int aw0 = ((2 * ah)     ^ aswz) * 8;
    const int aw1 = ((2 * ah + 1) ^ aswz) * 8;

    // ---- B gload staging: 2 instrs/wave covering 16 rows x 4 chunks each;
    //      lane l -> row l>>2, slot l&3, src chunk (l&3)^(((l>>2)&15)>>1 &3)
    const int brow = lane >> 2;                       // 0..15
    const int bgch = (lane & 3) ^ ((brow >> 1) & 3);  // pre-swizzled chunk
    const bf16* Bbase =
        Bbf + (size_t)(col0 + w * 16 + brow) * HIDDEN + bgch * 8;

    float4 aR[4];
    f32x4 acc[4][4] = {};

#define A_LOAD(KT)                                                        \
    { const float4* p_ = (const float4*)(Asrc + (KT) * 32);               \
      aR[0] = p_[0]; aR[1] = p_[1]; aR[2] = p_[2]; aR[3] = p_[3]; }

#define A_CVT_WRITE(BUF)                                                  \
    {                                                                     \
        bf16x8 t0 = { (bf16)aR[0].x, (bf16)aR[0].y, (bf16)aR[0].z,        \
                      (bf16)aR[0].w, (bf16)aR[1].x, (bf16)aR[1].y,        \
                      (bf16)aR[1].z, (bf16)aR[1].w };                     \
        bf16x8 t1 = { (bf16)aR[2].x, (bf16)aR[2].y, (bf16)aR[2].z,        \
                      (bf16)aR[2].w, (bf16)aR[3].x, (bf16)aR[3].y,        \
                      (bf16)aR[3].z, (bf16)aR[3].w };                     \
        *(bf16x8*)&As[BUF][arow][aw0] = t0;                               \
        *(bf16x8*)&As[BUF][arow][aw1] = t1;                               \
    }

#define B_GLDS(KT, BUF)                                                   \
    __builtin_amdgcn_global_load_lds(                                     \
        (const __attribute__((address_space(1))) void*)(Bbase + (KT) * 32),\
        (__attribute__((address_space(3))) void*)&Bs[BUF][w * 16][0],     \
        16, 0, 0);                                                        \
    __builtin_amdgcn_global_load_lds(                                     \
        (const __attribute__((address_space(1))) void*)                   \
            (Bbase + (size_t)64 * HIDDEN + (KT) * 32),                    \
        (__attribute__((address_space(3))) void*)&Bs[BUF][64 + w * 16][0],\
        16, 0, 0);

#define TILE_COMPUTE(BUF)                                                 \
    {                                                                     \
        bf16x8 afr[4], bfr[4];                                            \
        _Pragma("unroll") for (int j = 0; j < 4; ++j)                     \
            afr[j] = *(const bf16x8*)                                     \
                &As[BUF][wm * 64 + j * 16 + lr][colA];                    \
        _Pragma("unroll") for (int n = 0; n < 4; ++n)                     \
            bfr[n] = *(const bf16x8*)&Bs[BUF][wn * 64 + n * 16 + lr][colA];\
        __builtin_amdgcn_s_setprio(1);                                    \
        _Pragma("unroll") for (int j = 0; j < 4; ++j)                     \
            _Pragma("unroll") for (int n = 0; n < 4; ++n)                 \
                acc[j][n] = __builtin_amdgcn_mfma_f32_16x16x32_bf16(      \
                    afr[j], bfr[n], acc[j][n], 0, 0, 0);                  \
        __builtin_amdgcn_s_setprio(0);                                    \
    }

    // ---- prologue: stage tile 0 into buf0 ----
    A_LOAD(0)
    B_GLDS(0, 0)
    A_CVT_WRITE(0)
    __syncthreads();

    // ---- tiles 0..30: issue A(t+1) early, B gload(t+1), compute(t),
    //      cvt+write A(t+1), barrier ----
    for (int i = 0; i < 15; ++i) {
        const int t = i * 2;
        A_LOAD(t + 1)
        B_GLDS(t + 1, 1)
        TILE_COMPUTE(0)
        A_CVT_WRITE(1)
        __syncthreads();
        A_LOAD(t + 2)
        B_GLDS(t + 2, 0)
        TILE_COMPUTE(1)
        A_CVT_WRITE(0)
        __syncthreads();
    }
    A_LOAD(31)
    B_GLDS(31, 1)
    TILE_COMPUTE(0)
    A_CVT_WRITE(1)
    __syncthreads();
    // tile 31: compute only
    TILE_COMPUTE(1)

    // ------------------- epilogue: tanh + dot(W_v) reduction ----------------
    const int bidx = row0 >> 11;          // 128-row tiles never straddle batch
    float hlv[4], wcv[4], wvv[4];
#pragma unroll
    for (int n = 0; n < 4; ++n) {
        int g = col0 + wn * 64 + n * 16 + lr;
        hlv[n] = hl_plus[bidx * HIDDEN + g];
        wcv[n] = W_cov[g];
        wvv[n] = W_v[g];
    }
#pragma unroll
    for (int j = 0; j < 4; ++j) {
#pragma unroll
        for (int i = 0; i < 4; ++i) {
            int rloc = wm * 64 + j * 16 + kb * 4 + i;
            float cv = cov[row0 + rloc];
            float ep = 0.f;
#pragma unroll
            for (int n = 0; n < 4; ++n) {
                float arg = acc[j][n][i] + hlv[n] + cv * wcv[n];
                ep += tanh_fast(arg) * wvv[n];
            }
            ep += __shfl_xor(ep, 1);
            ep += __shfl_xor(ep, 2);
            ep += __shfl_xor(ep, 4);
            ep += __shfl_xor(ep, 8);
            if (lr == 0) e_buf[rloc][wn] = ep;
        }
    }
    __syncthreads();
    if (tid < 128)
        e_part[(size_t)nt * M_TOT + row0 + tid] = e_buf[tid][0] + e_buf[tid][1];

#undef A_LOAD
#undef A_CVT_WRITE
#undef B_GLDS
#undef TILE_COMPUTE
}

// ---------------------------------------------------------------------------
// Kernel 3: per-batch softmax over S=2048; also emits cov_new = cov + a
// ---------------------------------------------------------------------------
__global__ __launch_bounds__(256) void k_softmax(
    const float* __restrict__ e_part, const float* __restrict__ mask,
    const float* __restrict__ cov, const float* __restrict__ b_v,
    float* __restrict__ a_out, float* __restrict__ cov_out)
{
    __shared__ float red[8];
    int b = blockIdx.x, tid = threadIdx.x;
    float bv = b_v[0];
    float ev[8];
    float mx = -1e30f;
#pragma unroll
    for (int j = 0; j < 8; ++j) {
        int s = j * 256 + tid;
        int idx = b * S_SZ + s;
        float e = bv;
#pragma unroll
        for (int p = 0; p < 8; ++p) e += e_part[(size_t)p * M_TOT + idx];
        e += mask[idx] * MASKED_BIAS;
        ev[j] = e;
        mx = fmaxf(mx, e);
    }
#pragma unroll
    for (int off = 32; off; off >>= 1) mx = fmaxf(mx, __shfl_xor(mx, off));
    if ((tid & 63) == 0) red[tid >> 6] = mx;
    __syncthreads();
    mx = fmaxf(fmaxf(red[0], red[1]), fmaxf(red[2], red[3]));
    float sum = 0.f;
#pragma unroll
    for (int j = 0; j < 8; ++j) { ev[j] = __expf(ev[j] - mx); sum += ev[j]; }
#pragma unroll
    for (int off = 32; off; off >>= 1) sum += __shfl_xor(sum, off);
    if ((tid & 63) == 0) red[4 + (tid >> 6)] = sum;
    __syncthreads();
    sum = red[4] + red[5] + red[6] + red[7];
    float inv = 1.f / sum;
#pragma unroll
    for (int j = 0; j < 8; ++j) {
        int idx = b * S_SZ + j * 256 + tid;
        float a = ev[j] * inv;
        a_out[idx]   = a;
        cov_out[idx] = cov[idx] + a;
    }
}

// ---------------------------------------------------------------------------
// Kernel 4: context partials  part_out[b][sc][h] = sum_{s in chunk} a*K
// (f32 K; L3-warm after the GEMM streamed it)
// ---------------------------------------------------------------------------
__global__ __launch_bounds__(256) void k_ctx_part(
    const float* __restrict__ Kin, const float* __restrict__ a_out,
    float* __restrict__ part_out)
{
    int sc = blockIdx.x;   // 0..7
    int b  = blockIdx.y;   // 0..31
    int tid = threadIdx.x;
    const float4* Kb = (const float4*)(Kin + ((size_t)b * S_SZ + sc * 256) * HIDDEN);
    const float*  ab = a_out + b * S_SZ + sc * 256;
    float4 acc = {0.f, 0.f, 0.f, 0.f};
#pragma unroll 4
    for (int s = 0; s < 256; ++s) {
        float av = ab[s];
        float4 kv = Kb[(size_t)s * 256 + tid];
        acc.x += av * kv.x; acc.y += av * kv.y;
        acc.z += av * kv.z; acc.w += av * kv.w;
    }
    ((float4*)part_out)[((size_t)b * 8 + sc) * 256 + tid] = acc;
}

// ---------------------------------------------------------------------------
// Kernel 5: out[b][h] = sum_sc part_out[b][sc][h]
// ---------------------------------------------------------------------------
__global__ __launch_bounds__(256) void k_ctx_reduce(
    const float* __restrict__ part_out, float* __restrict__ out, int nc)
{
    int b = blockIdx.x, tid = threadIdx.x;
    float4 acc = {0.f, 0.f, 0.f, 0.f};
    for (int sc = 0; sc < nc; ++sc) {
        float4 v = ((const float4*)part_out)[((size_t)b * nc + sc) * 256 + tid];
        acc.x += v.x; acc.y += v.y; acc.z += v.z; acc.w += v.w;
    }
    ((float4*)out)[b * 256 + tid] = acc;
}

// ---------------------------------------------------------------------------
extern "C" void kernel_launch(void* const* d_in, const int* in_sizes, int n_in,
                              void* d_out, int out_size, void* d_ws, size_t ws_size,
                              hipStream_t stream)
{
    const float* h     = (const float*)d_in[0];
    const float* Kin   = (const float*)d_in[1];
    const float* cov   = (const float*)d_in[2];
    const float* mask  = (const float*)d_in[3];
    const float* W_h   = (const float*)d_in[4];
    const float* b_h   = (const float*)d_in[5];
    const float* W_K   = (const float*)d_in[6];
    const float* b_K   = (const float*)d_in[7];
    const float* W_cov = (const float*)d_in[8];
    const float* b_cov = (const float*)d_in[9];
    const float* W_v   = (const float*)d_in[10];
    const float* b_v   = (const float*)d_in[11];

    float* out_ctx = (float*)d_out;            // 32*1024
    float* a_out   = out_ctx + B_SZ * HIDDEN;  // 32*2048
    float* cov_out = a_out + M_TOT;            // 32*2048

    float* ws       = (float*)d_ws;
    float* hl_plus  = ws;                        // 32768 f32
    float* e_part   = ws + 32768;                // 8*65536 f32 = 2 MB
    float* part_out = e_part;                    // alias (sequential use, 1 MB)
    bf16*  Bbf      = (bf16*)(e_part + 8 * M_TOT);   // 2 MB
    // total ws use: ~4.2 MB (no Kbf)

    k_wconv<<<512, 256, 0, stream>>>(W_K, Bbf);
    k_hlplus<<<8192, 256, 0, stream>>>(h, W_h, b_h, b_K, b_cov, hl_plus);
    k_fusedC<<<512 * NT_N, 256, 0, stream>>>(
        Kin, Bbf, hl_plus, W_cov, cov, W_v, e_part);
    k_softmax<<<B_SZ, 256, 0, stream>>>(e_part, mask, cov, b_v, a_out, cov_out);
    dim3 g4(8, B_SZ);
    k_ctx_part<<<g4, 256, 0, stream>>>(Kin, a_out, part_out);
    k_ctx_reduce<<<B_SZ, 256, 0, stream>>>(part_out, out_ctx, 8);
}

// Round 15
// 273.468 us; speedup vs baseline: 1.3836x; 1.0717x over previous
//
#include <hip/hip_runtime.h>
#include <hip/hip_bf16.h>

#define HIDDEN 1024
#define B_SZ 32
#define S_SZ 2048
#define M_TOT (B_SZ * S_SZ)          // 65536 rows
#define MASKED_BIAS -10000.0f

using bf16   = __bf16;
using bf16x4 = __attribute__((ext_vector_type(4))) __bf16;
using bf16x8 = __attribute__((ext_vector_type(8))) __bf16;
using f32x4  = __attribute__((ext_vector_type(4))) float;

__device__ __forceinline__ float tanh_fast(float x) {
    float xc = fminf(fmaxf(x, -15.f), 15.f);
    float e2 = __expf(2.f * xc);
    return (e2 - 1.f) * __frcp_rn(e2 + 1.f);
}

// ---------------------------------------------------------------------------
// Kernel 0a: W_K f32 -> bf16 (2 MB, L2-resident B operand)
// ---------------------------------------------------------------------------
__global__ __launch_bounds__(256) void k_wconv(
    const float* __restrict__ W, bf16* __restrict__ out)
{
    int i = blockIdx.x * 256 + threadIdx.x;
    const float4* p = (const float4*)W + (size_t)i * 2;
    float4 a = p[0], b = p[1];
    bf16x8 v = { (bf16)a.x, (bf16)a.y, (bf16)a.z, (bf16)a.w,
                 (bf16)b.x, (bf16)b.y, (bf16)b.z, (bf16)b.w };
    *(bf16x8*)(out + (size_t)i * 8) = v;
}

// ---------------------------------------------------------------------------
// Kernel 0b: K f32 -> bf16 (128 MB A operand). Grid-stride 2048 blocks;
// non-temporal f32 loads via ext-vector type (f32 K never read again by a
// BW-bound consumer -> keep L3 for Kbf).
// ---------------------------------------------------------------------------
__global__ __launch_bounds__(256) void k_kconv(
    const float* __restrict__ K, bf16* __restrict__ out)
{
    const size_t n8     = (size_t)M_TOT * HIDDEN / 8;   // 8Mi groups of 8
    const size_t stride = (size_t)gridDim.x * 256;
    for (size_t i = (size_t)blockIdx.x * 256 + threadIdx.x; i < n8; i += stride) {
        const f32x4* p = (const f32x4*)K + i * 2;
        f32x4 a = __builtin_nontemporal_load(p);
        f32x4 b = __builtin_nontemporal_load(p + 1);
        bf16x8 v = { (bf16)a[0], (bf16)a[1], (bf16)a[2], (bf16)a[3],
                     (bf16)b[0], (bf16)b[1], (bf16)b[2], (bf16)b[3] };
        *(bf16x8*)(out + i * 8) = v;
    }
}

// ---------------------------------------------------------------------------
// Kernel 1: hl_plus[b][g] = dot(h[b,:], W_h[g,:]) + b_h[g] + b_K[g] + b_cov[g]
// ---------------------------------------------------------------------------
__global__ __launch_bounds__(256) void k_hlplus(
    const float* __restrict__ h, const float* __restrict__ W_h,
    const float* __restrict__ b_h, const float* __restrict__ b_K,
    const float* __restrict__ b_cov, float* __restrict__ hl_plus)
{
    int wid  = blockIdx.x * 4 + (threadIdx.x >> 6);
    int lane = threadIdx.x & 63;
    int b = wid & 31;
    int g = wid >> 5;
    const float4* hv = (const float4*)(h + b * HIDDEN);
    const float4* wv = (const float4*)(W_h + g * HIDDEN);
    float acc = 0.f;
#pragma unroll
    for (int i = 0; i < 4; ++i) {
        float4 a = hv[i * 64 + lane];
        float4 w = wv[i * 64 + lane];
        acc += a.x * w.x + a.y * w.y + a.z * w.z + a.w * w.w;
    }
#pragma unroll
    for (int off = 32; off; off >>= 1) acc += __shfl_xor(acc, off);
    if (lane == 0)
        hl_plus[b * HIDDEN + g] = acc + b_h[g] + b_K[g] + b_cov[g];
}

// ===========================================================================
// Kernel 2 (best measured, R9 config): fused GEMM+tanh+dot.
// Tile 256x128, BK=32, 512 threads = 8 waves as 4M x 2N -> wave tile 64x64.
// All staging via global_load_lds from bf16; one __syncthreads per K-tile;
// conflict-free XOR swizzle: LDS[row][chunk c] = global chunk c ^ ((row>>1)&3).
// ===========================================================================
#define NT_N 8

__global__ __launch_bounds__(512, 4) void k_fused9(
    const bf16*  __restrict__ Kbf,      // [65536][1024] bf16
    const bf16*  __restrict__ Bbf,      // [1024][1024] bf16 (W_K)
    const float* __restrict__ hl_plus,
    const float* __restrict__ W_cov,
    const float* __restrict__ cov,
    const float* __restrict__ W_v,
    float* __restrict__ e_part)         // [8][65536]
{
    __shared__ __align__(16) bf16 As[2][256][32];   // 32 KB
    __shared__ __align__(16) bf16 Bs[2][128][32];   // 16 KB
    __shared__ float e_buf[256][2];

    const int tid = threadIdx.x;
    const int bid = blockIdx.x;
    // XCD-bijective swizzle: 2048 blocks, 256/XCD, nt fastest within XCD.
    const int lid = (bid & 7) * 256 + (bid >> 3);
    const int mt  = lid >> 3;            // 256 m-tiles (256 rows)
    const int nt  = lid & 7;             // 8 n-tiles (128 cols)
    const int row0 = mt * 256;
    const int col0 = nt * 128;

    const int w    = tid >> 6;           // wave 0..7
    const int lane = tid & 63;
    const int wm   = w >> 1;             // M-quarter (64 rows)
    const int wn   = w & 1;              // N-half    (64 cols)
    const int lr   = lane & 15;
    const int kb   = lane >> 4;
    const int colA = (kb ^ ((lr >> 1) & 3)) * 8;   // read-side swizzled col

    // stage geometry: one gload instr per wave = 16 rows x 64B (4x16B chunks);
    // source chunk pre-swizzled: lane l -> chunk (l&3) ^ ((l>>3)&3)
    const int srow = lane >> 2;
    const int gch  = (lane & 3) ^ ((lane >> 3) & 3);
    const bf16* Abase = Kbf + (size_t)(row0 + w * 16 + srow) * HIDDEN + gch * 8;
    const bf16* Bbase = Bbf + (size_t)(col0 + w * 16 + srow) * HIDDEN + gch * 8;

    f32x4 acc[4][4] = {};

    // 3 gloads/thread per K-tile: A rows [0,128)+[128,256), B rows [0,128)
#define STAGE(KT, BUF)                                                    \
    __builtin_amdgcn_global_load_lds(                                     \
        (const __attribute__((address_space(1))) void*)(Abase + (KT) * 32),\
        (__attribute__((address_space(3))) void*)&As[BUF][w * 16][0],     \
        16, 0, 0);                                                        \
    __builtin_amdgcn_global_load_lds(                                     \
        (const __attribute__((address_space(1))) void*)                   \
            (Abase + (size_t)128 * HIDDEN + (KT) * 32),                   \
        (__attribute__((address_space(3))) void*)&As[BUF][128 + w * 16][0],\
        16, 0, 0);                                                        \
    __builtin_amdgcn_global_load_lds(                                     \
        (const __attribute__((address_space(1))) void*)(Bbase + (KT) * 32),\
        (__attribute__((address_space(3))) void*)&Bs[BUF][w * 16][0],     \
        16, 0, 0);

#define TILE_COMPUTE(BUF)                                                 \
    {                                                                     \
        bf16x8 afr[4], bfr[4];                                            \
        _Pragma("unroll") for (int j = 0; j < 4; ++j)                     \
            afr[j] = *(const bf16x8*)                                     \
                &As[BUF][wm * 64 + j * 16 + lr][colA];                    \
        _Pragma("unroll") for (int n = 0; n < 4; ++n)                     \
            bfr[n] = *(const bf16x8*)&Bs[BUF][wn * 64 + n * 16 + lr][colA];\
        __builtin_amdgcn_s_setprio(1);                                    \
        _Pragma("unroll") for (int j = 0; j < 4; ++j)                     \
            _Pragma("unroll") for (int n = 0; n < 4; ++n)                 \
                acc[j][n] = __builtin_amdgcn_mfma_f32_16x16x32_bf16(      \
                    afr[j], bfr[n], acc[j][n], 0, 0, 0);                  \
        __builtin_amdgcn_s_setprio(0);                                    \
    }

    // prologue: stage tile 0 into buf0 (drained by __syncthreads)
    STAGE(0, 0)
    __syncthreads();

    // tiles 0..29 (stage t+1 each; one barrier per tile)
    for (int i = 0; i < 15; ++i) {
        const int t = i * 2;
        STAGE(t + 1, 1)          // tile t   reads buf0, stages t+1 -> buf1
        TILE_COMPUTE(0)
        __syncthreads();
        STAGE(t + 2, 0)          // tile t+1 reads buf1, stages t+2 -> buf0
        TILE_COMPUTE(1)
        __syncthreads();
    }
    // tile 30: stage 31 -> buf1
    STAGE(31, 1)
    TILE_COMPUTE(0)
    __syncthreads();
    // tile 31: compute only
    TILE_COMPUTE(1)

    // ------------------- epilogue: tanh + dot(W_v) reduction ----------------
    const int bidx = row0 >> 11;
    float hlv[4], wcv[4], wvv[4];
#pragma unroll
    for (int n = 0; n < 4; ++n) {
        int g = col0 + wn * 64 + n * 16 + lr;
        hlv[n] = hl_plus[bidx * HIDDEN + g];
        wcv[n] = W_cov[g];
        wvv[n] = W_v[g];
    }
#pragma unroll
    for (int j = 0; j < 4; ++j) {
#pragma unroll
        for (int i = 0; i < 4; ++i) {
            int rloc = wm * 64 + j * 16 + kb * 4 + i;
            float cv = cov[row0 + rloc];
            float ep = 0.f;
#pragma unroll
            for (int n = 0; n < 4; ++n) {
                float arg = acc[j][n][i] + hlv[n] + cv * wcv[n];
                ep += tanh_fast(arg) * wvv[n];
            }
            ep += __shfl_xor(ep, 1);
            ep += __shfl_xor(ep, 2);
            ep += __shfl_xor(ep, 4);
            ep += __shfl_xor(ep, 8);
            if (lr == 0) e_buf[rloc][wn] = ep;
        }
    }
    __syncthreads();
    if (tid < 256)
        e_part[(size_t)nt * M_TOT + row0 + tid] = e_buf[tid][0] + e_buf[tid][1];

#undef STAGE
#undef TILE_COMPUTE
}

// ---------------------------------------------------------------------------
// Kernel 3: per-batch softmax over S=2048; also emits cov_new = cov + a
// ---------------------------------------------------------------------------
__global__ __launch_bounds__(256) void k_softmax(
    const float* __restrict__ e_part, const float* __restrict__ mask,
    const float* __restrict__ cov, const float* __restrict__ b_v,
    float* __restrict__ a_out, float* __restrict__ cov_out)
{
    __shared__ float red[8];
    int b = blockIdx.x, tid = threadIdx.x;
    float bv = b_v[0];
    float ev[8];
    float mx = -1e30f;
#pragma unroll
    for (int j = 0; j < 8; ++j) {
        int s = j * 256 + tid;
        int idx = b * S_SZ + s;
        float e = bv;
#pragma unroll
        for (int p = 0; p < 8; ++p) e += e_part[(size_t)p * M_TOT + idx];
        e += mask[idx] * MASKED_BIAS;
        ev[j] = e;
        mx = fmaxf(mx, e);
    }
#pragma unroll
    for (int off = 32; off; off >>= 1) mx = fmaxf(mx, __shfl_xor(mx, off));
    if ((tid & 63) == 0) red[tid >> 6] = mx;
    __syncthreads();
    mx = fmaxf(fmaxf(red[0], red[1]), fmaxf(red[2], red[3]));
    float sum = 0.f;
#pragma unroll
    for (int j = 0; j < 8; ++j) { ev[j] = __expf(ev[j] - mx); sum += ev[j]; }
#pragma unroll
    for (int off = 32; off; off >>= 1) sum += __shfl_xor(sum, off);
    if ((tid & 63) == 0) red[4 + (tid >> 6)] = sum;
    __syncthreads();
    sum = red[4] + red[5] + red[6] + red[7];
    float inv = 1.f / sum;
#pragma unroll
    for (int j = 0; j < 8; ++j) {
        int idx = b * S_SZ + j * 256 + tid;
        float a = ev[j] * inv;
        a_out[idx]   = a;
        cov_out[idx] = cov[idx] + a;
    }
}

// ---------------------------------------------------------------------------
// Kernel 4: context partials from bf16 K (L3-warm after GEMM), 16 s-chunks
// ---------------------------------------------------------------------------
__global__ __launch_bounds__(256) void k_ctx_part_bf(
    const bf16* __restrict__ Kbf, const float* __restrict__ a_out,
    float* __restrict__ part_out)
{
    int sc = blockIdx.x;   // 0..15
    int b  = blockIdx.y;   // 0..31
    int tid = threadIdx.x;
    const bf16* Kb = Kbf + ((size_t)b * S_SZ + sc * 128) * HIDDEN;
    const float* ab = a_out + b * S_SZ + sc * 128;
    float4 acc = {0.f, 0.f, 0.f, 0.f};
#pragma unroll 4
    for (int s = 0; s < 128; ++s) {
        float av = ab[s];
        bf16x4 kv = *(const bf16x4*)(Kb + (size_t)s * HIDDEN + tid * 4);
        acc.x += av * (float)kv[0];
        acc.y += av * (float)kv[1];
        acc.z += av * (float)kv[2];
        acc.w += av * (float)kv[3];
    }
    ((float4*)part_out)[((size_t)b * 16 + sc) * 256 + tid] = acc;
}

// ---------------------------------------------------------------------------
// Kernel 5: out[b][h] = sum_sc part_out[b][sc][h]
// ---------------------------------------------------------------------------
__global__ __launch_bounds__(256) void k_ctx_reduce(
    const float* __restrict__ part_out, float* __restrict__ out, int nc)
{
    int b = blockIdx.x, tid = threadIdx.x;
    float4 acc = {0.f, 0.f, 0.f, 0.f};
    for (int sc = 0; sc < nc; ++sc) {
        float4 v = ((const float4*)part_out)[((size_t)b * nc + sc) * 256 + tid];
        acc.x += v.x; acc.y += v.y; acc.z += v.z; acc.w += v.w;
    }
    ((float4*)out)[b * 256 + tid] = acc;
}

// ---------------------------------------------------------------------------
extern "C" void kernel_launch(void* const* d_in, const int* in_sizes, int n_in,
                              void* d_out, int out_size, void* d_ws, size_t ws_size,
                              hipStream_t stream)
{
    const float* h     = (const float*)d_in[0];
    const float* Kin   = (const float*)d_in[1];
    const float* cov   = (const float*)d_in[2];
    const float* mask  = (const float*)d_in[3];
    const float* W_h   = (const float*)d_in[4];
    const float* b_h   = (const float*)d_in[5];
    const float* W_K   = (const float*)d_in[6];
    const float* b_K   = (const float*)d_in[7];
    const float* W_cov = (const float*)d_in[8];
    const float* b_cov = (const float*)d_in[9];
    const float* W_v   = (const float*)d_in[10];
    const float* b_v   = (const float*)d_in[11];

    float* out_ctx = (float*)d_out;            // 32*1024
    float* a_out   = out_ctx + B_SZ * HIDDEN;  // 32*2048
    float* cov_out = a_out + M_TOT;            // 32*2048

    float* ws       = (float*)d_ws;
    float* hl_plus  = ws;                        // 32768 f32
    float* e_part   = ws + 32768;                // 8*65536 f32 = 2 MB
    float* part_out = e_part;                    // alias (sequential use, 2 MB)
    bf16*  Bbf      = (bf16*)(e_part + 8 * M_TOT);          // 2 MB
    bf16*  Kbf      = (bf16*)((char*)Bbf + (size_t)HIDDEN * HIDDEN * sizeof(bf16));

    k_wconv<<<512, 256, 0, stream>>>(W_K, Bbf);
    k_hlplus<<<8192, 256, 0, stream>>>(h, W_h, b_h, b_K, b_cov, hl_plus);
    k_kconv<<<2048, 256, 0, stream>>>(Kin, Kbf);
    k_fused9<<<256 * NT_N, 512, 0, stream>>>(
        Kbf, Bbf, hl_plus, W_cov, cov, W_v, e_part);
    k_softmax<<<B_SZ, 256, 0, stream>>>(e_part, mask, cov, b_v, a_out, cov_out);
    dim3 g4(16, B_SZ);
    k_ctx_part_bf<<<g4, 256, 0, stream>>>(Kbf, a_out, part_out);
    k_ctx_reduce<<<B_SZ, 256, 0, stream>>>(part_out, out_ctx, 16);
}

// Round 16
// 268.537 us; speedup vs baseline: 1.4090x; 1.0184x over previous
//
#include <hip/hip_runtime.h>
#include <hip/hip_bf16.h>

#define HIDDEN 1024
#define B_SZ 32
#define S_SZ 2048
#define M_TOT (B_SZ * S_SZ)          // 65536 rows
#define MASKED_BIAS -10000.0f

using bf16   = __bf16;
using bf16x4 = __attribute__((ext_vector_type(4))) __bf16;
using bf16x8 = __attribute__((ext_vector_type(8))) __bf16;
using f32x4  = __attribute__((ext_vector_type(4))) float;

__device__ __forceinline__ float tanh_fast(float x) {
    float xc = fminf(fmaxf(x, -15.f), 15.f);
    float e2 = __expf(2.f * xc);
    return (e2 - 1.f) * __frcp_rn(e2 + 1.f);
}

// ===========================================================================
// Kernel 0 (R16): fused prep. Block ranges:
//   [0,2048)     : K f32->bf16 grid-stride, NT loads (keep dead f32 out of L3)
//   [2048,2560)  : W_K f32->bf16 (2 MB)
//   [2560,3072)  : hl_plus = h@W_h^T + b_h + b_K + b_cov
//                  (2048 waves x 16 dots; b fixed per wave -> h-row in regs)
// wconv+hlplus ride inside kconv's BW shadow (they were ~11 us serial).
// ===========================================================================
#define KCONV_BLKS 2048

__global__ __launch_bounds__(256) void k_prep(
    const float* __restrict__ K,   bf16* __restrict__ Kbf,
    const float* __restrict__ W,   bf16* __restrict__ Wbf,
    const float* __restrict__ h,   const float* __restrict__ W_h,
    const float* __restrict__ b_h, const float* __restrict__ b_K,
    const float* __restrict__ b_cov, float* __restrict__ hl_plus)
{
    const int bid = blockIdx.x;
    const int tid = threadIdx.x;

    if (bid < KCONV_BLKS) {
        // ---- kconv: 128 MB bf16 out of 256 MB f32, NT loads ----
        const size_t n8     = (size_t)M_TOT * HIDDEN / 8;
        const size_t stride = (size_t)KCONV_BLKS * 256;
        for (size_t i = (size_t)bid * 256 + tid; i < n8; i += stride) {
            const f32x4* p = (const f32x4*)K + i * 2;
            f32x4 a = __builtin_nontemporal_load(p);
            f32x4 b = __builtin_nontemporal_load(p + 1);
            bf16x8 v = { (bf16)a[0], (bf16)a[1], (bf16)a[2], (bf16)a[3],
                         (bf16)b[0], (bf16)b[1], (bf16)b[2], (bf16)b[3] };
            *(bf16x8*)(Kbf + i * 8) = v;
        }
    } else if (bid < KCONV_BLKS + 512) {
        // ---- wconv: 1Mi elems, 8 per thread ----
        int i = (bid - KCONV_BLKS) * 256 + tid;
        const f32x4* p = (const f32x4*)W + (size_t)i * 2;
        f32x4 a = p[0], b = p[1];
        bf16x8 v = { (bf16)a[0], (bf16)a[1], (bf16)a[2], (bf16)a[3],
                     (bf16)b[0], (bf16)b[1], (bf16)b[2], (bf16)b[3] };
        *(bf16x8*)(Wbf + (size_t)i * 8) = v;
    } else {
        // ---- hlplus: wave wv handles dots wv + 2048*k (k<16):
        //      b = wv&31 fixed, g = (wv>>5) + 64k ----
        int wv   = (bid - (KCONV_BLKS + 512)) * 4 + (tid >> 6);  // 0..2047
        int lane = tid & 63;
        int b    = wv & 31;
        int g0   = wv >> 5;                                      // 0..63
        const float4* hv = (const float4*)(h + b * HIDDEN);
        float4 ha[4];
#pragma unroll
        for (int i = 0; i < 4; ++i) ha[i] = hv[i * 64 + lane];
#pragma unroll 4
        for (int k = 0; k < 16; ++k) {
            int g = g0 + 64 * k;
            const float4* wv4 = (const float4*)(W_h + (size_t)g * HIDDEN);
            float acc = 0.f;
#pragma unroll
            for (int i = 0; i < 4; ++i) {
                float4 w = wv4[i * 64 + lane];
                acc += ha[i].x * w.x + ha[i].y * w.y +
                       ha[i].z * w.z + ha[i].w * w.w;
            }
#pragma unroll
            for (int off = 32; off; off >>= 1) acc += __shfl_xor(acc, off);
            if (lane == 0)
                hl_plus[b * HIDDEN + g] = acc + b_h[g] + b_K[g] + b_cov[g];
        }
    }
}

// ===========================================================================
// Kernel 2 (best measured, R9/R15 config): fused GEMM+tanh+dot.
// Tile 256x128, BK=32, 512 threads = 8 waves as 4M x 2N -> wave tile 64x64.
// All staging via global_load_lds from bf16; one __syncthreads per K-tile;
// conflict-free XOR swizzle: LDS[row][chunk c] = global chunk c ^ ((row>>1)&3).
// ===========================================================================
#define NT_N 8

__global__ __launch_bounds__(512, 4) void k_fused9(
    const bf16*  __restrict__ Kbf,      // [65536][1024] bf16
    const bf16*  __restrict__ Bbf,      // [1024][1024] bf16 (W_K)
    const float* __restrict__ hl_plus,
    const float* __restrict__ W_cov,
    const float* __restrict__ cov,
    const float* __restrict__ W_v,
    float* __restrict__ e_part)         // [8][65536]
{
    __shared__ __align__(16) bf16 As[2][256][32];   // 32 KB
    __shared__ __align__(16) bf16 Bs[2][128][32];   // 16 KB
    __shared__ float e_buf[256][2];

    const int tid = threadIdx.x;
    const int bid = blockIdx.x;
    // XCD-bijective swizzle: 2048 blocks, 256/XCD, nt fastest within XCD.
    const int lid = (bid & 7) * 256 + (bid >> 3);
    const int mt  = lid >> 3;            // 256 m-tiles (256 rows)
    const int nt  = lid & 7;             // 8 n-tiles (128 cols)
    const int row0 = mt * 256;
    const int col0 = nt * 128;

    const int w    = tid >> 6;           // wave 0..7
    const int lane = tid & 63;
    const int wm   = w >> 1;             // M-quarter (64 rows)
    const int wn   = w & 1;              // N-half    (64 cols)
    const int lr   = lane & 15;
    const int kb   = lane >> 4;
    const int colA = (kb ^ ((lr >> 1) & 3)) * 8;   // read-side swizzled col

    // stage geometry: one gload instr per wave = 16 rows x 64B (4x16B chunks);
    // source chunk pre-swizzled: lane l -> chunk (l&3) ^ ((l>>3)&3)
    const int srow = lane >> 2;
    const int gch  = (lane & 3) ^ ((lane >> 3) & 3);
    const bf16* Abase = Kbf + (size_t)(row0 + w * 16 + srow) * HIDDEN + gch * 8;
    const bf16* Bbase = Bbf + (size_t)(col0 + w * 16 + srow) * HIDDEN + gch * 8;

    f32x4 acc[4][4] = {};

    // 3 gloads/thread per K-tile: A rows [0,128)+[128,256), B rows [0,128)
#define STAGE(KT, BUF)                                                    \
    __builtin_amdgcn_global_load_lds(                                     \
        (const __attribute__((address_space(1))) void*)(Abase + (KT) * 32),\
        (__attribute__((address_space(3))) void*)&As[BUF][w * 16][0],     \
        16, 0, 0);                                                        \
    __builtin_amdgcn_global_load_lds(                                     \
        (const __attribute__((address_space(1))) void*)                   \
            (Abase + (size_t)128 * HIDDEN + (KT) * 32),                   \
        (__attribute__((address_space(3))) void*)&As[BUF][128 + w * 16][0],\
        16, 0, 0);                                                        \
    __builtin_amdgcn_global_load_lds(                                     \
        (const __attribute__((address_space(1))) void*)(Bbase + (KT) * 32),\
        (__attribute__((address_space(3))) void*)&Bs[BUF][w * 16][0],     \
        16, 0, 0);

#define TILE_COMPUTE(BUF)                                                 \
    {                                                                     \
        bf16x8 afr[4], bfr[4];                                            \
        _Pragma("unroll") for (int j = 0; j < 4; ++j)                     \
            afr[j] = *(const bf16x8*)                                     \
                &As[BUF][wm * 64 + j * 16 + lr][colA];                    \
        _Pragma("unroll") for (int n = 0; n < 4; ++n)                     \
            bfr[n] = *(const bf16x8*)&Bs[BUF][wn * 64 + n * 16 + lr][colA];\
        __builtin_amdgcn_s_setprio(1);                                    \
        _Pragma("unroll") for (int j = 0; j < 4; ++j)                     \
            _Pragma("unroll") for (int n = 0; n < 4; ++n)                 \
                acc[j][n] = __builtin_amdgcn_mfma_f32_16x16x32_bf16(      \
                    afr[j], bfr[n], acc[j][n], 0, 0, 0);                  \
        __builtin_amdgcn_s_setprio(0);                                    \
    }

    // prologue: stage tile 0 into buf0 (drained by __syncthreads)
    STAGE(0, 0)
    __syncthreads();

    // tiles 0..29 (stage t+1 each; one barrier per tile)
    for (int i = 0; i < 15; ++i) {
        const int t = i * 2;
        STAGE(t + 1, 1)          // tile t   reads buf0, stages t+1 -> buf1
        TILE_COMPUTE(0)
        __syncthreads();
        STAGE(t + 2, 0)          // tile t+1 reads buf1, stages t+2 -> buf0
        TILE_COMPUTE(1)
        __syncthreads();
    }
    // tile 30: stage 31 -> buf1
    STAGE(31, 1)
    TILE_COMPUTE(0)
    __syncthreads();
    // tile 31: compute only
    TILE_COMPUTE(1)

    // ------------------- epilogue: tanh + dot(W_v) reduction ----------------
    const int bidx = row0 >> 11;
    float hlv[4], wcv[4], wvv[4];
#pragma unroll
    for (int n = 0; n < 4; ++n) {
        int g = col0 + wn * 64 + n * 16 + lr;
        hlv[n] = hl_plus[bidx * HIDDEN + g];
        wcv[n] = W_cov[g];
        wvv[n] = W_v[g];
    }
#pragma unroll
    for (int j = 0; j < 4; ++j) {
#pragma unroll
        for (int i = 0; i < 4; ++i) {
            int rloc = wm * 64 + j * 16 + kb * 4 + i;
            float cv = cov[row0 + rloc];
            float ep = 0.f;
#pragma unroll
            for (int n = 0; n < 4; ++n) {
                float arg = acc[j][n][i] + hlv[n] + cv * wcv[n];
                ep += tanh_fast(arg) * wvv[n];
            }
            ep += __shfl_xor(ep, 1);
            ep += __shfl_xor(ep, 2);
            ep += __shfl_xor(ep, 4);
            ep += __shfl_xor(ep, 8);
            if (lr == 0) e_buf[rloc][wn] = ep;
        }
    }
    __syncthreads();
    if (tid < 256)
        e_part[(size_t)nt * M_TOT + row0 + tid] = e_buf[tid][0] + e_buf[tid][1];

#undef STAGE
#undef TILE_COMPUTE
}

// ---------------------------------------------------------------------------
// Kernel 3: per-batch softmax over S=2048; also emits cov_new = cov + a
// ---------------------------------------------------------------------------
__global__ __launch_bounds__(256) void k_softmax(
    const float* __restrict__ e_part, const float* __restrict__ mask,
    const float* __restrict__ cov, const float* __restrict__ b_v,
    float* __restrict__ a_out, float* __restrict__ cov_out)
{
    __shared__ float red[8];
    int b = blockIdx.x, tid = threadIdx.x;
    float bv = b_v[0];
    float ev[8];
    float mx = -1e30f;
#pragma unroll
    for (int j = 0; j < 8; ++j) {
        int s = j * 256 + tid;
        int idx = b * S_SZ + s;
        float e = bv;
#pragma unroll
        for (int p = 0; p < 8; ++p) e += e_part[(size_t)p * M_TOT + idx];
        e += mask[idx] * MASKED_BIAS;
        ev[j] = e;
        mx = fmaxf(mx, e);
    }
#pragma unroll
    for (int off = 32; off; off >>= 1) mx = fmaxf(mx, __shfl_xor(mx, off));
    if ((tid & 63) == 0) red[tid >> 6] = mx;
    __syncthreads();
    mx = fmaxf(fmaxf(red[0], red[1]), fmaxf(red[2], red[3]));
    float sum = 0.f;
#pragma unroll
    for (int j = 0; j < 8; ++j) { ev[j] = __expf(ev[j] - mx); sum += ev[j]; }
#pragma unroll
    for (int off = 32; off; off >>= 1) sum += __shfl_xor(sum, off);
    if ((tid & 63) == 0) red[4 + (tid >> 6)] = sum;
    __syncthreads();
    sum = red[4] + red[5] + red[6] + red[7];
    float inv = 1.f / sum;
#pragma unroll
    for (int j = 0; j < 8; ++j) {
        int idx = b * S_SZ + j * 256 + tid;
        float a = ev[j] * inv;
        a_out[idx]   = a;
        cov_out[idx] = cov[idx] + a;
    }
}

// ---------------------------------------------------------------------------
// Kernel 4: context partials from bf16 K (L3-warm after GEMM), 16 s-chunks
// ---------------------------------------------------------------------------
__global__ __launch_bounds__(256) void k_ctx_part_bf(
    const bf16* __restrict__ Kbf, const float* __restrict__ a_out,
    float* __restrict__ part_out)
{
    int sc = blockIdx.x;   // 0..15
    int b  = blockIdx.y;   // 0..31
    int tid = threadIdx.x;
    const bf16* Kb = Kbf + ((size_t)b * S_SZ + sc * 128) * HIDDEN;
    const float* ab = a_out + b * S_SZ + sc * 128;
    float4 acc = {0.f, 0.f, 0.f, 0.f};
#pragma unroll 4
    for (int s = 0; s < 128; ++s) {
        float av = ab[s];
        bf16x4 kv = *(const bf16x4*)(Kb + (size_t)s * HIDDEN + tid * 4);
        acc.x += av * (float)kv[0];
        acc.y += av * (float)kv[1];
        acc.z += av * (float)kv[2];
        acc.w += av * (float)kv[3];
    }
    ((float4*)part_out)[((size_t)b * 16 + sc) * 256 + tid] = acc;
}

// ---------------------------------------------------------------------------
// Kernel 5: out[b][h] = sum_sc part_out[b][sc][h]
// ---------------------------------------------------------------------------
__global__ __launch_bounds__(256) void k_ctx_reduce(
    const float* __restrict__ part_out, float* __restrict__ out, int nc)
{
    int b = blockIdx.x, tid = threadIdx.x;
    float4 acc = {0.f, 0.f, 0.f, 0.f};
    for (int sc = 0; sc < nc; ++sc) {
        float4 v = ((const float4*)part_out)[((size_t)b * nc + sc) * 256 + tid];
        acc.x += v.x; acc.y += v.y; acc.z += v.z; acc.w += v.w;
    }
    ((float4*)out)[b * 256 + tid] = acc;
}

// ---------------------------------------------------------------------------
extern "C" void kernel_launch(void* const* d_in, const int* in_sizes, int n_in,
                              void* d_out, int out_size, void* d_ws, size_t ws_size,
                              hipStream_t stream)
{
    const float* h     = (const float*)d_in[0];
    const float* Kin   = (const float*)d_in[1];
    const float* cov   = (const float*)d_in[2];
    const float* mask  = (const float*)d_in[3];
    const float* W_h   = (const float*)d_in[4];
    const float* b_h   = (const float*)d_in[5];
    const float* W_K   = (const float*)d_in[6];
    const float* b_K   = (const float*)d_in[7];
    const float* W_cov = (const float*)d_in[8];
    const float* b_cov = (const float*)d_in[9];
    const float* W_v   = (const float*)d_in[10];
    const float* b_v   = (const float*)d_in[11];

    float* out_ctx = (float*)d_out;            // 32*1024
    float* a_out   = out_ctx + B_SZ * HIDDEN;  // 32*2048
    float* cov_out = a_out + M_TOT;            // 32*2048

    float* ws       = (float*)d_ws;
    float* hl_plus  = ws;                        // 32768 f32
    float* e_part   = ws + 32768;                // 8*65536 f32 = 2 MB
    float* part_out = e_part;                    // alias (sequential use, 2 MB)
    bf16*  Bbf      = (bf16*)(e_part + 8 * M_TOT);          // 2 MB
    bf16*  Kbf      = (bf16*)((char*)Bbf + (size_t)HIDDEN * HIDDEN * sizeof(bf16));

    k_prep<<<KCONV_BLKS + 512 + 512, 256, 0, stream>>>(
        Kin, Kbf, W_K, Bbf, h, W_h, b_h, b_K, b_cov, hl_plus);
    k_fused9<<<256 * NT_N, 512, 0, stream>>>(
        Kbf, Bbf, hl_plus, W_cov, cov, W_v, e_part);
    k_softmax<<<B_SZ, 256, 0, stream>>>(e_part, mask, cov, b_v, a_out, cov_out);
    dim3 g4(16, B_SZ);
    k_ctx_part_bf<<<g4, 256, 0, stream>>>(Kbf, a_out, part_out);
    k_ctx_reduce<<<B_SZ, 256, 0, stream>>>(part_out, out_ctx, 16);
}